// Round 6
// baseline (956.338 us; speedup 1.0000x reference)
//
#include <hip/hip_runtime.h>
#include <hip/hip_bf16.h>
#include <stdint.h>

typedef unsigned short u16;
typedef __attribute__((ext_vector_type(8))) short bf16x8;   // 8 bf16 in 4 VGPRs
typedef __attribute__((ext_vector_type(4))) float f32x4;
typedef __attribute__((ext_vector_type(4))) unsigned short us4;

#define T_TOK   23328      // 32*729 tokens
#define MPAD    23424      // 183*128 (padded M for 128-tiles)
#define DMODEL  1152
#define N3      3456
#define NHEAD   16
#define HDIM    72
#define SEQ     729
#define VSTR    736        // vT row stride (729 padded; 736*2B = 16B-aligned rows)
#define SCALE_F 0.1178511301977579f   // 72^-0.5, folded into q at QKV epilogue
#define KVB     64
#define NT      12         // ceil(729/64)
#define THR     8.0f       // defer-max threshold (natural-log domain, P <= e^8)

__device__ __forceinline__ u16 f2bf(float f) {
  unsigned u = __builtin_bit_cast(unsigned, f);
  u += 0x7fffu + ((u >> 16) & 1u);   // RNE
  return (u16)(u >> 16);
}

__device__ __forceinline__ f32x4 mfma16(bf16x8 a, bf16x8 b, f32x4 c) {
  return __builtin_amdgcn_mfma_f32_16x16x32_bf16(a, b, c, 0, 0, 0);
}

// async global->LDS, 16B per lane; lds ptr must be wave-uniform (computed from wave id only)
#define GL16(g, l)                                                        \
  __builtin_amdgcn_global_load_lds(                                       \
      (const __attribute__((address_space(1))) void*)(g),                 \
      (__attribute__((address_space(3))) void*)(l), 16, 0, 0)

// ---------------- conversion kernels ----------------

__global__ void k_cvt_hidden(const float* __restrict__ in, u16* __restrict__ out) {
  size_t i4 = ((size_t)blockIdx.x * blockDim.x + threadIdx.x) * 4;
  if (i4 >= (size_t)MPAD * DMODEL) return;
  us4 o;
  if (i4 < (size_t)T_TOK * DMODEL) {
    float4 v = *(const float4*)(in + i4);
    o[0] = f2bf(v.x); o[1] = f2bf(v.y); o[2] = f2bf(v.z); o[3] = f2bf(v.w);
  } else {
    o[0] = 0; o[1] = 0; o[2] = 0; o[3] = 0;
  }
  *(us4*)(out + i4) = o;
}

template <int R, int C>
__global__ void k_transpose(const float* __restrict__ w, u16* __restrict__ wt) {
  size_t i = (size_t)blockIdx.x * blockDim.x + threadIdx.x;
  if (i >= (size_t)R * C) return;
  int n  = (int)(i / R);
  int kk = (int)(i - (size_t)n * R);
  wt[i] = f2bf(w[(size_t)kk * C + n]);
}

// ---------------- GEMM v2: 128x128 tile, BK=32, 4 waves, 2-phase dbuf + XCD swizzle ----------
// v2 changes vs round-5 (targeting the 60% stall share: MfmaUtil 22 + VALU 19, nothing saturated):
//  (1) double-buffered LDS, stage(t+1) issued BEFORE compute(t), ONE barrier per K-step —
//      stage loads get ~16 MFMA + 8 ds_read of latency cover instead of zero (T3-minimum).
//  (2) 1D grid + bijective XCD-chunk swizzle (m204): same-A-panel blocks co-locate on one
//      XCD's L2 -> cut the 10x A-panel re-fetch (FETCH 641 MB vs 62 MB ideal).
// GX = n-tiles per m-row (27 for QKV, 9 for out-proj).
template <int EPI, int GX>
__global__ __launch_bounds__(256) void k_gemm(
    const u16* __restrict__ A, const u16* __restrict__ Bt,
    const float* __restrict__ bias,
    u16* __restrict__ qo, u16* __restrict__ ko, u16* __restrict__ vTo,
    float* __restrict__ outp)
{
  __shared__ u16 As[2][4096];   // [buf][128 rows x 32 cols]
  __shared__ u16 Bs[2][4096];
  const int tid  = threadIdx.x;
  const int wave = tid >> 6;
  const int lane = tid & 63;

  // bijective XCD-chunk remap (nwg = GX*183, generally % 8 != 0 -> m204 variant)
  constexpr int nwg = GX * 183;
  constexpr int q8 = nwg >> 3, r8 = nwg & 7;
  const int bid = blockIdx.x;
  const int xcd = bid & 7, idx = bid >> 3;
  const int wgid = (xcd < r8 ? xcd * (q8 + 1) : r8 * (q8 + 1) + (xcd - r8) * q8) + idx;
  const int m0 = (wgid / GX) * 128;
  const int n0 = (wgid % GX) * 128;

  const int wm = (wave >> 1) * 64;
  const int wn = (wave & 1) * 64;

  // staging map: per buf, LDS byte = half*4096 + wave*1024 + lane*16
  const int rofs = wave * 16 + (lane >> 2);
  const int cofs = (lane & 3) * 8;
  const u16* gA0 = A  + (size_t)(m0 + rofs) * DMODEL + cofs;
  const u16* gA1 = gA0 + (size_t)64 * DMODEL;
  const u16* gB0 = Bt + (size_t)(n0 + rofs) * DMODEL + cofs;
  const u16* gB1 = gB0 + (size_t)64 * DMODEL;

  const int fr = lane & 15;
  const int fk = (lane >> 4) * 8;

  auto stage = [&](int kt, int b) {
    char* a_ = (char*)As + b * 8192 + wave * 1024;
    char* b_ = (char*)Bs + b * 8192 + wave * 1024;
    GL16(gA0 + kt, a_);
    GL16(gA1 + kt, a_ + 4096);
    GL16(gB0 + kt, b_);
    GL16(gB1 + kt, b_ + 4096);
  };

  f32x4 acc[4][4] = {};

  stage(0, 0);
  __syncthreads();                      // drain vmcnt -> buf0 visible

  int buf = 0;
  for (int kt = 0; kt < DMODEL; kt += 32) {
    if (kt + 32 < DMODEL)
      stage(kt + 32, buf ^ 1);          // issue next tile early: MFMA below covers latency
    bf16x8 af[4], bfrag[4];
#pragma unroll
    for (int i = 0; i < 4; ++i)
      af[i] = *(const bf16x8*)&As[buf][(wm + i * 16 + fr) * 32 + fk];
#pragma unroll
    for (int j = 0; j < 4; ++j)
      bfrag[j] = *(const bf16x8*)&Bs[buf][(wn + j * 16 + fr) * 32 + fk];
#pragma unroll
    for (int i = 0; i < 4; ++i)
#pragma unroll
      for (int j = 0; j < 4; ++j)
        acc[i][j] = mfma16(af[i], bfrag[j], acc[i][j]);
    __syncthreads();                    // next tile staged + all waves done reading buf
    buf ^= 1;
  }

  // epilogue. C-frag layout: col = lane&15, row = (lane>>4)*4 + reg  [m89-verified]
#pragma unroll
  for (int j = 0; j < 4; ++j) {
    const int n = n0 + wn + j * 16 + fr;
    const float bi = bias[n];
    if (EPI == 0) {
      const int which = n / DMODEL;
      const int rr = n - which * DMODEL;
      const int h = rr / HDIM;
      const int d = rr - h * HDIM;
#pragma unroll
      for (int i = 0; i < 4; ++i) {
        const int tr = m0 + wm + i * 16 + (lane >> 4) * 4;
#pragma unroll
        for (int rg = 0; rg < 4; ++rg) {
          const int t = tr + rg;
          if (t < T_TOK) {
            const int bb = t / SEQ;
            const int s  = t - bb * SEQ;
            const int bh = bb * NHEAD + h;
            const float val = acc[i][j][rg] + bi;
            if (which == 0)
              qo[((size_t)bh * SEQ + s) * HDIM + d] = f2bf(val * SCALE_F);
            else if (which == 1)
              ko[((size_t)bh * SEQ + s) * HDIM + d] = f2bf(val);
            else
              vTo[((size_t)bh * HDIM + d) * VSTR + s] = f2bf(val);
          }
        }
      }
    } else {
#pragma unroll
      for (int i = 0; i < 4; ++i) {
        const int tr = m0 + wm + i * 16 + (lane >> 4) * 4;
#pragma unroll
        for (int rg = 0; rg < 4; ++rg) {
          const int t = tr + rg;
          if (t < T_TOK)
            outp[(size_t)t * DMODEL + n] = acc[i][j][rg] + bi;
        }
      }
    }
  }
}

// ---------------- flash attention v2.1 (unchanged from round 5) ----------------

// stage one 64-key K tile (64x72, 144B rows, 576 chunks) + V tile (72x64, swizzled, 576 chunks)
__device__ __forceinline__ void stage_kv(const u16* __restrict__ kb, const u16* __restrict__ vb,
                                         u16* KsB, u16* VsB, int kt, int wv, int lane) {
#pragma unroll
  for (int rdi = 0; rdi < 2; ++rdi) {
    const int c0 = rdi * 256 + wv * 64;       // wave-uniform chunk base
    {
      const int c = c0 + lane;
      const int row = c / 9;                  // 144B rows = 9 chunks
      const int off = (c - row * 9) * 8;
      GL16(kb + (size_t)(kt + row) * HDIM + off, KsB + (size_t)c0 * 8);
    }
    {
      const int c = c0 + lane;
      const int d = c >> 3;                   // 128B rows = 8 chunks
      int off = kt + (((c & 7) ^ (d & 7)) << 3);   // pre-swizzled source (rule 21)
      off = off > (VSTR - 8) ? (VSTR - 8) : off;   // clamp: keys>=729 are masked anyway
      GL16(vb + (size_t)d * VSTR + off, VsB + (size_t)c0 * 8);
    }
  }
  if (wv == 0) {                              // chunks 512..575
    const int c = 512 + lane;
    const int row = c / 9;
    const int off = (c - row * 9) * 8;
    GL16(kb + (size_t)(kt + row) * HDIM + off, KsB + (size_t)512 * 8);
    const int d = c >> 3;
    int voff = kt + (((c & 7) ^ (d & 7)) << 3);
    voff = voff > (VSTR - 8) ? (VSTR - 8) : voff;
    GL16(vb + (size_t)d * VSTR + voff, VsB + (size_t)512 * 8);
  }
}

__global__ __launch_bounds__(256) void k_attn(
    const u16* __restrict__ q, const u16* __restrict__ k,
    const u16* __restrict__ vT, u16* __restrict__ aout)
{
  // Ks: 64x72 + 32-elem pad (kf2 over-read spill stays in-array; pad zeroed at init)
  // Vs: 80x64 (rows 72..79: row72 = 1.0 ones-column, 73..79 zeroed)
  __shared__ alignas(16) u16 Ks[2][4640];
  __shared__ alignas(16) u16 Vs[2][5120];
  __shared__ alignas(16) u16 pl[4][16][72];   // per-wave P tile, 144B pitch

  const int tid  = threadIdx.x;
  const int wv   = tid >> 6;
  const int lane = tid & 63;
  const int fr = lane & 15;
  const int fg = lane >> 4;
  const int fk = fg * 8;

  const int bh = blockIdx.y;
  const int qbase = blockIdx.x * 64 + wv * 16;

  const u16* qb = q  + (size_t)bh * (SEQ * HDIM);
  const u16* kb = k  + (size_t)bh * (SEQ * HDIM);
  const u16* vb = vT + (size_t)bh * (HDIM * VSTR);

  // one-time LDS init (staging never touches these regions):
  //  - V ones-column row 72 (denominator trick) + zero rows 73..79
  //  - Ks 32-elem pad x2 buffers (kf2 over-read target) — MUST be zero, not uninit
  if (tid < 64) { Vs[0][4608 + tid] = 0x3F80; Vs[1][4608 + tid] = 0x3F80; }
  for (int i = tid; i < 448; i += 256) { Vs[0][4672 + i] = 0; Vs[1][4672 + i] = 0; }
  if (tid < 32) { Ks[0][4608 + tid] = 0; Ks[1][4608 + tid] = 0; }

  // Q fragments (hd=72 = 32+32+8); qf2 nonzero only for fg==0 (k-slots 72..95 are zero)
  const int qrow = qbase + fr;
  bf16x8 qf0 = {}, qf1 = {}, qf2 = {};
  if (qrow < SEQ) {
    const u16* qp = qb + (size_t)qrow * HDIM;
    qf0 = *(const bf16x8*)(qp + fk);
    qf1 = *(const bf16x8*)(qp + 32 + fk);
    if (fg == 0) qf2 = *(const bf16x8*)(qp + 64);
  }

  f32x4 oacc[5] = {};                   // d-tiles 0..3: output; 4: d=64..71 + l at fr==8
  float mrun[4] = {-1e30f, -1e30f, -1e30f, -1e30f};

  stage_kv(kb, vb, Ks[0], Vs[0], 0, wv, lane);
  __syncthreads();

  int buf = 0;
  for (int t = 0; t < NT; ++t) {
    const int kt = t * KVB;
    if (t + 1 < NT)
      stage_kv(kb, vb, Ks[buf ^ 1], Vs[buf ^ 1], kt + KVB, wv, lane);

    // ---- QK^T: 4 halves of 16 keys ----
    const char* kB = (const char*)Ks[buf];
    f32x4 sc[4];
#pragma unroll
    for (int hh = 0; hh < 4; ++hh) {
      const char* krow = kB + (hh * 16 + fr) * 144;
      bf16x8 kf0 = *(const bf16x8*)(krow + fg * 16);
      bf16x8 kf1 = *(const bf16x8*)(krow + 64 + fg * 16);
      bf16x8 kf2 = *(const bf16x8*)(krow + 128 + fg * 16);  // fg>0: next-row data or zeroed pad; A-side is 0
      f32x4 z = {};
      z = mfma16(qf0, kf0, z);
      z = mfma16(qf1, kf1, z);
      z = mfma16(qf2, kf2, z);
      sc[hh] = z;
    }
    if (kt + KVB > SEQ) {               // tail tile: mask invalid keys (col = fr)
#pragma unroll
      for (int hh = 0; hh < 4; ++hh)
        if (kt + hh * 16 + fr >= SEQ) {
          sc[hh][0] = -1e30f; sc[hh][1] = -1e30f; sc[hh][2] = -1e30f; sc[hh][3] = -1e30f;
        }
    }

    // ---- online softmax, defer-max ----
    float tmx[4];
    bool needs = false;
#pragma unroll
    for (int r = 0; r < 4; ++r) {
      tmx[r] = fmaxf(fmaxf(sc[0][r], sc[1][r]), fmaxf(sc[2][r], sc[3][r]));
      needs |= (tmx[r] > mrun[r] + THR);
    }
    if (__any(needs)) {                 // wave-uniform rescale path
#pragma unroll
      for (int r = 0; r < 4; ++r) {
        float tm = tmx[r];
        tm = fmaxf(tm, __shfl_xor(tm, 1));
        tm = fmaxf(tm, __shfl_xor(tm, 2));
        tm = fmaxf(tm, __shfl_xor(tm, 4));
        tm = fmaxf(tm, __shfl_xor(tm, 8));
        const float mnew = fmaxf(mrun[r], tm);
        const float resc = __expf(mrun[r] - mnew);
        mrun[r] = mnew;
#pragma unroll
        for (int v = 0; v < 5; ++v) oacc[v][r] *= resc;
      }
    }
#pragma unroll
    for (int r = 0; r < 4; ++r) {
      const int prow = fg * 4 + r;      // C-frag row = q-row within wave tile
#pragma unroll
      for (int hh = 0; hh < 4; ++hh)
        pl[wv][prow][hh * 16 + fr] = f2bf(__expf(sc[hh][r] - mrun[r]));
    }

    // ---- PV: P[16x64] x V[64x80] (d=72 col of V = 1.0 -> l) ----
    const bf16x8 pa0 = *(const bf16x8*)&pl[wv][fr][fk];        // keys 0..31
    const bf16x8 pa1 = *(const bf16x8*)&pl[wv][fr][32 + fk];   // keys 32..63
    const char* vB = (const char*)Vs[buf];
    const int swz = (fr & 7) << 4;
#pragma unroll
    for (int v = 0; v < 5; ++v) {
      const char* vrow = vB + (size_t)(v * 16 + fr) * 128;
      bf16x8 vf0 = *(const bf16x8*)(vrow + ((fg * 16) ^ swz));
      bf16x8 vf1 = *(const bf16x8*)(vrow + (((4 + fg) * 16) ^ swz));
      oacc[v] = mfma16(pa0, vf0, oacc[v]);
      oacc[v] = mfma16(pa1, vf1, oacc[v]);
    }

    __syncthreads();                    // next tile staged + all waves done with buf
    buf ^= 1;
  }

  // ---- epilogue: l lives in oacc[4][r] at lane fr==8 of each fg group ----
  const int bb = bh >> 4, h = bh & 15;
#pragma unroll
  for (int r = 0; r < 4; ++r) {
    const int row = qbase + fg * 4 + r;
    if (row < SEQ) {
      const float l = __shfl(oacc[4][r], (lane & 48) | 8);
      const float inv = 1.0f / l;
      u16* op = aout + (size_t)(bb * SEQ + row) * DMODEL + h * HDIM;
#pragma unroll
      for (int v = 0; v < 5; ++v) {
        const int d = v * 16 + fr;
        if (d < HDIM) op[d] = f2bf(oacc[v][r] * inv);
      }
    }
  }
}

// ---------------- launch ----------------
extern "C" void kernel_launch(void* const* d_in, const int* in_sizes, int n_in,
                              void* d_out, int out_size, void* d_ws, size_t ws_size,
                              hipStream_t stream) {
  (void)in_sizes; (void)n_in; (void)out_size; (void)ws_size;
  const float* hs   = (const float*)d_in[0];
  const float* wqkv = (const float*)d_in[1];
  const float* bqkv = (const float*)d_in[2];
  const float* wout = (const float*)d_in[3];
  const float* bout = (const float*)d_in[4];
  float* out = (float*)d_out;

  u16* hbuf  = (u16*)d_ws;                        // [MPAD][1152] bf16: hidden, later attn_out
  u16* wqkvT = hbuf  + (size_t)MPAD * DMODEL;     // [3456][1152]
  u16* woutT = wqkvT + (size_t)N3 * DMODEL;       // [1152][1152]
  u16* qb    = woutT + (size_t)DMODEL * DMODEL;   // [512][729][72]
  u16* kb    = qb    + (size_t)512 * SEQ * HDIM;  // [512][729][72]
  u16* vTb   = kb    + (size_t)512 * SEQ * HDIM;  // [512][72][736]
  // note: attn K/V tail-tile staging reads up to 39 rows past a bh's K rows / clamped within
  // VSTR for V — always inside [kb, vTb end) -> in-bounds of d_ws, values masked by P=0.

  k_cvt_hidden<<<(MPAD * DMODEL / 4 + 255) / 256, 256, 0, stream>>>(hs, hbuf);
  k_transpose<DMODEL, N3><<<((size_t)DMODEL * N3 + 255) / 256, 256, 0, stream>>>(wqkv, wqkvT);
  k_transpose<DMODEL, DMODEL><<<((size_t)DMODEL * DMODEL + 255) / 256, 256, 0, stream>>>(wout, woutT);
  k_gemm<0, 27><<<27 * 183, 256, 0, stream>>>(hbuf, wqkvT, bqkv, qb, kb, vTb, nullptr);
  k_attn<<<dim3(12, 512), 256, 0, stream>>>(qb, kb, vTb, hbuf);
  k_gemm<1, 9><<<9 * 183, 256, 0, stream>>>(hbuf, woutT, bout, nullptr, nullptr, nullptr, out);
}

// Round 8
// 887.710 us; speedup vs baseline: 1.0773x; 1.0773x over previous
//
#include <hip/hip_runtime.h>
#include <hip/hip_bf16.h>
#include <stdint.h>

typedef unsigned short u16;
typedef __attribute__((ext_vector_type(8))) short bf16x8;   // 8 bf16 in 4 VGPRs
typedef __attribute__((ext_vector_type(4))) float f32x4;
typedef __attribute__((ext_vector_type(4))) unsigned short us4;

#define T_TOK   23328      // 32*729 tokens
#define MPAD    23424      // 183*128 (padded M for 128-tiles)
#define DMODEL  1152
#define N3      3456
#define NHEAD   16
#define HDIM    72
#define SEQ     729
#define VSTR    736        // vT row stride (729 padded; 736*2B = 16B-aligned rows)
#define SCALE_F 0.1178511301977579f   // 72^-0.5, folded into q at QKV epilogue
#define KVB     64
#define NT      12         // ceil(729/64)
#define THR     8.0f       // defer-max threshold (natural-log domain, P <= e^8)

__device__ __forceinline__ u16 f2bf(float f) {
  unsigned u = __builtin_bit_cast(unsigned, f);
  u += 0x7fffu + ((u >> 16) & 1u);   // RNE
  return (u16)(u >> 16);
}

__device__ __forceinline__ f32x4 mfma16(bf16x8 a, bf16x8 b, f32x4 c) {
  return __builtin_amdgcn_mfma_f32_16x16x32_bf16(a, b, c, 0, 0, 0);
}

// async global->LDS, 16B per lane; lds ptr must be wave-uniform (computed from wave id only)
#define GL16(g, l)                                                        \
  __builtin_amdgcn_global_load_lds(                                       \
      (const __attribute__((address_space(1))) void*)(g),                 \
      (__attribute__((address_space(3))) void*)(l), 16, 0, 0)

// ---------------- conversion kernels ----------------

__global__ void k_cvt_hidden(const float* __restrict__ in, u16* __restrict__ out) {
  size_t i4 = ((size_t)blockIdx.x * blockDim.x + threadIdx.x) * 4;
  if (i4 >= (size_t)MPAD * DMODEL) return;
  us4 o;
  if (i4 < (size_t)T_TOK * DMODEL) {
    float4 v = *(const float4*)(in + i4);
    o[0] = f2bf(v.x); o[1] = f2bf(v.y); o[2] = f2bf(v.z); o[3] = f2bf(v.w);
  } else {
    o[0] = 0; o[1] = 0; o[2] = 0; o[3] = 0;
  }
  *(us4*)(out + i4) = o;
}

template <int R, int C>
__global__ void k_transpose(const float* __restrict__ w, u16* __restrict__ wt) {
  size_t i = (size_t)blockIdx.x * blockDim.x + threadIdx.x;
  if (i >= (size_t)R * C) return;
  int n  = (int)(i / R);
  int kk = (int)(i - (size_t)n * R);
  wt[i] = f2bf(w[(size_t)kk * C + n]);
}

// ---------------- GEMM v3: 128x128, BK=32, dbuf + counted vmcnt (T4) + XCD swizzle ----------
// v3 vs v2 (round 6 regressed 366->477): round-6's __syncthreads after MFMA = vmcnt(0) DRAIN,
// killing the prefetch each K-step. v3 uses raw s_barriers and a counted vmcnt(4):
//   stage(t+1); vmcnt(4)+bar (all waves' tile-t loads published); ds_read+MFMA(t); bar.
// Prefetch loads stay in flight across the whole compute phase; never drained to 0 mid-loop.
template <int EPI, int GX>
__global__ __launch_bounds__(256) void k_gemm(
    const u16* __restrict__ A, const u16* __restrict__ Bt,
    const float* __restrict__ bias,
    u16* __restrict__ qo, u16* __restrict__ ko, u16* __restrict__ vTo,
    float* __restrict__ outp)
{
  __shared__ u16 As[2][4096];   // [buf][128 rows x 32 cols]
  __shared__ u16 Bs[2][4096];
  const int tid  = threadIdx.x;
  const int wave = tid >> 6;
  const int lane = tid & 63;

  // bijective XCD-chunk remap (nwg % 8 != 0 -> m204 variant)
  constexpr int nwg = GX * 183;
  constexpr int q8 = nwg >> 3, r8 = nwg & 7;
  const int bid = blockIdx.x;
  const int xcd = bid & 7, idx = bid >> 3;
  const int wgid = (xcd < r8 ? xcd * (q8 + 1) : r8 * (q8 + 1) + (xcd - r8) * q8) + idx;
  const int m0 = (wgid / GX) * 128;
  const int n0 = (wgid % GX) * 128;

  const int wm = (wave >> 1) * 64;
  const int wn = (wave & 1) * 64;

  // staging map: per buf, LDS byte = half*4096 + wave*1024 + lane*16
  const int rofs = wave * 16 + (lane >> 2);
  const int cofs = (lane & 3) * 8;
  const u16* gA0 = A  + (size_t)(m0 + rofs) * DMODEL + cofs;
  const u16* gA1 = gA0 + (size_t)64 * DMODEL;
  const u16* gB0 = Bt + (size_t)(n0 + rofs) * DMODEL + cofs;
  const u16* gB1 = gB0 + (size_t)64 * DMODEL;

  const int fr = lane & 15;
  const int fk = (lane >> 4) * 8;

  auto stage = [&](int kt, int b) {
    char* a_ = (char*)As + b * 8192 + wave * 1024;
    char* b_ = (char*)Bs + b * 8192 + wave * 1024;
    GL16(gA0 + kt, a_);
    GL16(gA1 + kt, a_ + 4096);
    GL16(gB0 + kt, b_);
    GL16(gB1 + kt, b_ + 4096);
  };

  f32x4 acc[4][4] = {};

  stage(0, 0);                          // 4 loads in flight

  int buf = 0;
  for (int kt = 0; kt < DMODEL; kt += 32) {
    if (kt + 32 < DMODEL) {
      stage(kt + 32, buf ^ 1);          // +4 -> 8 in flight
      // own tile-t loads done (4 newest remain) + barrier publishes ALL waves' tile-t loads
      asm volatile("s_waitcnt vmcnt(4)\n\ts_barrier" ::: "memory");
    } else {
      asm volatile("s_waitcnt vmcnt(0)\n\ts_barrier" ::: "memory");
    }
    bf16x8 af[4], bfrag[4];
#pragma unroll
    for (int i = 0; i < 4; ++i)
      af[i] = *(const bf16x8*)&As[buf][(wm + i * 16 + fr) * 32 + fk];
#pragma unroll
    for (int j = 0; j < 4; ++j)
      bfrag[j] = *(const bf16x8*)&Bs[buf][(wn + j * 16 + fr) * 32 + fk];
#pragma unroll
    for (int i = 0; i < 4; ++i)
#pragma unroll
      for (int j = 0; j < 4; ++j)
        acc[i][j] = mfma16(af[i], bfrag[j], acc[i][j]);
    // all waves done reading buf (ds_reads consumed by MFMA dataflow) -> next iter may overwrite
    asm volatile("s_barrier" ::: "memory");
    buf ^= 1;
  }

  // epilogue. C-frag layout: col = lane&15, row = (lane>>4)*4 + reg  [m89-verified]
#pragma unroll
  for (int j = 0; j < 4; ++j) {
    const int n = n0 + wn + j * 16 + fr;
    const float bi = bias[n];
    if (EPI == 0) {
      const int which = n / DMODEL;
      const int rr = n - which * DMODEL;
      const int h = rr / HDIM;
      const int d = rr - h * HDIM;
#pragma unroll
      for (int i = 0; i < 4; ++i) {
        const int tr = m0 + wm + i * 16 + (lane >> 4) * 4;
#pragma unroll
        for (int rg = 0; rg < 4; ++rg) {
          const int t = tr + rg;
          if (t < T_TOK) {
            const int bb = t / SEQ;
            const int s  = t - bb * SEQ;
            const int bh = bb * NHEAD + h;
            const float val = acc[i][j][rg] + bi;
            if (which == 0)
              qo[((size_t)bh * SEQ + s) * HDIM + d] = f2bf(val * SCALE_F);
            else if (which == 1)
              ko[((size_t)bh * SEQ + s) * HDIM + d] = f2bf(val);
            else
              vTo[((size_t)bh * HDIM + d) * VSTR + s] = f2bf(val);
          }
        }
      }
    } else {
#pragma unroll
      for (int i = 0; i < 4; ++i) {
        const int tr = m0 + wm + i * 16 + (lane >> 4) * 4;
#pragma unroll
        for (int rg = 0; rg < 4; ++rg) {
          const int t = tr + rg;
          if (t < T_TOK)
            outp[(size_t)t * DMODEL + n] = acc[i][j][rg] + bi;
        }
      }
    }
  }
}

// ---------------- flash attention v2.1 (unchanged from round 5) ----------------

// stage one 64-key K tile (64x72, 144B rows, 576 chunks) + V tile (72x64, swizzled, 576 chunks)
__device__ __forceinline__ void stage_kv(const u16* __restrict__ kb, const u16* __restrict__ vb,
                                         u16* KsB, u16* VsB, int kt, int wv, int lane) {
#pragma unroll
  for (int rdi = 0; rdi < 2; ++rdi) {
    const int c0 = rdi * 256 + wv * 64;       // wave-uniform chunk base
    {
      const int c = c0 + lane;
      const int row = c / 9;                  // 144B rows = 9 chunks
      const int off = (c - row * 9) * 8;
      GL16(kb + (size_t)(kt + row) * HDIM + off, KsB + (size_t)c0 * 8);
    }
    {
      const int c = c0 + lane;
      const int d = c >> 3;                   // 128B rows = 8 chunks
      int off = kt + (((c & 7) ^ (d & 7)) << 3);   // pre-swizzled source (rule 21)
      off = off > (VSTR - 8) ? (VSTR - 8) : off;   // clamp: keys>=729 are masked anyway
      GL16(vb + (size_t)d * VSTR + off, VsB + (size_t)c0 * 8);
    }
  }
  if (wv == 0) {                              // chunks 512..575
    const int c = 512 + lane;
    const int row = c / 9;
    const int off = (c - row * 9) * 8;
    GL16(kb + (size_t)(kt + row) * HDIM + off, KsB + (size_t)512 * 8);
    const int d = c >> 3;
    int voff = kt + (((c & 7) ^ (d & 7)) << 3);
    voff = voff > (VSTR - 8) ? (VSTR - 8) : voff;
    GL16(vb + (size_t)d * VSTR + voff, VsB + (size_t)512 * 8);
  }
}

__global__ __launch_bounds__(256) void k_attn(
    const u16* __restrict__ q, const u16* __restrict__ k,
    const u16* __restrict__ vT, u16* __restrict__ aout)
{
  // Ks: 64x72 + 32-elem pad (kf2 over-read spill stays in-array; pad zeroed at init)
  // Vs: 80x64 (rows 72..79: row72 = 1.0 ones-column, 73..79 zeroed)
  __shared__ alignas(16) u16 Ks[2][4640];
  __shared__ alignas(16) u16 Vs[2][5120];
  __shared__ alignas(16) u16 pl[4][16][72];   // per-wave P tile, 144B pitch

  const int tid  = threadIdx.x;
  const int wv   = tid >> 6;
  const int lane = tid & 63;
  const int fr = lane & 15;
  const int fg = lane >> 4;
  const int fk = fg * 8;

  const int bh = blockIdx.y;
  const int qbase = blockIdx.x * 64 + wv * 16;

  const u16* qb = q  + (size_t)bh * (SEQ * HDIM);
  const u16* kb = k  + (size_t)bh * (SEQ * HDIM);
  const u16* vb = vT + (size_t)bh * (HDIM * VSTR);

  // one-time LDS init (staging never touches these regions):
  //  - V ones-column row 72 (denominator trick) + zero rows 73..79
  //  - Ks 32-elem pad x2 buffers (kf2 over-read target) — MUST be zero, not uninit
  if (tid < 64) { Vs[0][4608 + tid] = 0x3F80; Vs[1][4608 + tid] = 0x3F80; }
  for (int i = tid; i < 448; i += 256) { Vs[0][4672 + i] = 0; Vs[1][4672 + i] = 0; }
  if (tid < 32) { Ks[0][4608 + tid] = 0; Ks[1][4608 + tid] = 0; }

  // Q fragments (hd=72 = 32+32+8); qf2 nonzero only for fg==0 (k-slots 72..95 are zero)
  const int qrow = qbase + fr;
  bf16x8 qf0 = {}, qf1 = {}, qf2 = {};
  if (qrow < SEQ) {
    const u16* qp = qb + (size_t)qrow * HDIM;
    qf0 = *(const bf16x8*)(qp + fk);
    qf1 = *(const bf16x8*)(qp + 32 + fk);
    if (fg == 0) qf2 = *(const bf16x8*)(qp + 64);
  }

  f32x4 oacc[5] = {};                   // d-tiles 0..3: output; 4: d=64..71 + l at fr==8
  float mrun[4] = {-1e30f, -1e30f, -1e30f, -1e30f};

  stage_kv(kb, vb, Ks[0], Vs[0], 0, wv, lane);
  __syncthreads();

  int buf = 0;
  for (int t = 0; t < NT; ++t) {
    const int kt = t * KVB;
    if (t + 1 < NT)
      stage_kv(kb, vb, Ks[buf ^ 1], Vs[buf ^ 1], kt + KVB, wv, lane);

    // ---- QK^T: 4 halves of 16 keys ----
    const char* kB = (const char*)Ks[buf];
    f32x4 sc[4];
#pragma unroll
    for (int hh = 0; hh < 4; ++hh) {
      const char* krow = kB + (hh * 16 + fr) * 144;
      bf16x8 kf0 = *(const bf16x8*)(krow + fg * 16);
      bf16x8 kf1 = *(const bf16x8*)(krow + 64 + fg * 16);
      bf16x8 kf2 = *(const bf16x8*)(krow + 128 + fg * 16);  // fg>0: next-row data or zeroed pad; A-side is 0
      f32x4 z = {};
      z = mfma16(qf0, kf0, z);
      z = mfma16(qf1, kf1, z);
      z = mfma16(qf2, kf2, z);
      sc[hh] = z;
    }
    if (kt + KVB > SEQ) {               // tail tile: mask invalid keys (col = fr)
#pragma unroll
      for (int hh = 0; hh < 4; ++hh)
        if (kt + hh * 16 + fr >= SEQ) {
          sc[hh][0] = -1e30f; sc[hh][1] = -1e30f; sc[hh][2] = -1e30f; sc[hh][3] = -1e30f;
        }
    }

    // ---- online softmax, defer-max ----
    float tmx[4];
    bool needs = false;
#pragma unroll
    for (int r = 0; r < 4; ++r) {
      tmx[r] = fmaxf(fmaxf(sc[0][r], sc[1][r]), fmaxf(sc[2][r], sc[3][r]));
      needs |= (tmx[r] > mrun[r] + THR);
    }
    if (__any(needs)) {                 // wave-uniform rescale path
#pragma unroll
      for (int r = 0; r < 4; ++r) {
        float tm = tmx[r];
        tm = fmaxf(tm, __shfl_xor(tm, 1));
        tm = fmaxf(tm, __shfl_xor(tm, 2));
        tm = fmaxf(tm, __shfl_xor(tm, 4));
        tm = fmaxf(tm, __shfl_xor(tm, 8));
        const float mnew = fmaxf(mrun[r], tm);
        const float resc = __expf(mrun[r] - mnew);
        mrun[r] = mnew;
#pragma unroll
        for (int v = 0; v < 5; ++v) oacc[v][r] *= resc;
      }
    }
#pragma unroll
    for (int r = 0; r < 4; ++r) {
      const int prow = fg * 4 + r;      // C-frag row = q-row within wave tile
#pragma unroll
      for (int hh = 0; hh < 4; ++hh)
        pl[wv][prow][hh * 16 + fr] = f2bf(__expf(sc[hh][r] - mrun[r]));
    }

    // ---- PV: P[16x64] x V[64x80] (d=72 col of V = 1.0 -> l) ----
    const bf16x8 pa0 = *(const bf16x8*)&pl[wv][fr][fk];        // keys 0..31
    const bf16x8 pa1 = *(const bf16x8*)&pl[wv][fr][32 + fk];   // keys 32..63
    const char* vB = (const char*)Vs[buf];
    const int swz = (fr & 7) << 4;
#pragma unroll
    for (int v = 0; v < 5; ++v) {
      const char* vrow = vB + (size_t)(v * 16 + fr) * 128;
      bf16x8 vf0 = *(const bf16x8*)(vrow + ((fg * 16) ^ swz));
      bf16x8 vf1 = *(const bf16x8*)(vrow + (((4 + fg) * 16) ^ swz));
      oacc[v] = mfma16(pa0, vf0, oacc[v]);
      oacc[v] = mfma16(pa1, vf1, oacc[v]);
    }

    __syncthreads();                    // next tile staged + all waves done with buf
    buf ^= 1;
  }

  // ---- epilogue: l lives in oacc[4][r] at lane fr==8 of each fg group ----
  const int bb = bh >> 4, h = bh & 15;
#pragma unroll
  for (int r = 0; r < 4; ++r) {
    const int row = qbase + fg * 4 + r;
    if (row < SEQ) {
      const float l = __shfl(oacc[4][r], (lane & 48) | 8);
      const float inv = 1.0f / l;
      u16* op = aout + (size_t)(bb * SEQ + row) * DMODEL + h * HDIM;
#pragma unroll
      for (int v = 0; v < 5; ++v) {
        const int d = v * 16 + fr;
        if (d < HDIM) op[d] = f2bf(oacc[v][r] * inv);
      }
    }
  }
}

// ---------------- launch ----------------
extern "C" void kernel_launch(void* const* d_in, const int* in_sizes, int n_in,
                              void* d_out, int out_size, void* d_ws, size_t ws_size,
                              hipStream_t stream) {
  (void)in_sizes; (void)n_in; (void)out_size; (void)ws_size;
  const float* hs   = (const float*)d_in[0];
  const float* wqkv = (const float*)d_in[1];
  const float* bqkv = (const float*)d_in[2];
  const float* wout = (const float*)d_in[3];
  const float* bout = (const float*)d_in[4];
  float* out = (float*)d_out;

  u16* hbuf  = (u16*)d_ws;                        // [MPAD][1152] bf16: hidden, later attn_out
  u16* wqkvT = hbuf  + (size_t)MPAD * DMODEL;     // [3456][1152]
  u16* woutT = wqkvT + (size_t)N3 * DMODEL;       // [1152][1152]
  u16* qb    = woutT + (size_t)DMODEL * DMODEL;   // [512][729][72]
  u16* kb    = qb    + (size_t)512 * SEQ * HDIM;  // [512][729][72]
  u16* vTb   = kb    + (size_t)512 * SEQ * HDIM;  // [512][72][736]
  // note: attn K/V tail-tile staging reads up to 39 rows past a bh's K rows / clamped within
  // VSTR for V — always inside [kb, vTb end) -> in-bounds of d_ws, values masked by P=0.

  k_cvt_hidden<<<(MPAD * DMODEL / 4 + 255) / 256, 256, 0, stream>>>(hs, hbuf);
  k_transpose<DMODEL, N3><<<((size_t)DMODEL * N3 + 255) / 256, 256, 0, stream>>>(wqkv, wqkvT);
  k_transpose<DMODEL, DMODEL><<<((size_t)DMODEL * DMODEL + 255) / 256, 256, 0, stream>>>(wout, woutT);
  k_gemm<0, 27><<<27 * 183, 256, 0, stream>>>(hbuf, wqkvT, bqkv, qb, kb, vTb, nullptr);
  k_attn<<<dim3(12, 512), 256, 0, stream>>>(qb, kb, vTb, hbuf);
  k_gemm<1, 9><<<9 * 183, 256, 0, stream>>>(hbuf, woutT, bout, nullptr, nullptr, nullptr, out);
}